// Round 1
// baseline (453.854 us; speedup 1.0000x reference)
//
#include <hip/hip_runtime.h>

// ---------------------------------------------------------------------------
// GAT 2-layer fused pipeline for MI355X.
// Layer1: h = x@W1 [N,256]; per-head attention softmax over incoming edges
//         (CSR-sorted, no float atomics), bias+ReLU fused, then layer-2
//         projection h2 = hrelu@W2 [N,2] + attention coefficients fused into
//         the same per-node wave (hrelu never written to memory).
// Layer2: per-node 1-thread aggregation over 16B/node table.
// ---------------------------------------------------------------------------

#define F_IN 128
#define C1 256          // heads*hid = 8*32
#define NEG 0.2f

// ---------------- K1: x[N,128] @ W1[128,256] -> h[N,256] -------------------
// BM=64 rows, BN=256 (full), BK=16. 256 threads, 8x8 register tile.
__global__ __launch_bounds__(256) void gemm1_k(const float* __restrict__ x,
                                               const float* __restrict__ W,
                                               float* __restrict__ h, int N) {
    __shared__ float xs[16][64];    // transposed x tile: xs[k][r]
    __shared__ float wsm[16][256];  // W tile
    const int t = threadIdx.x;
    const int row0 = blockIdx.x * 64;
    const int tc = t & 31;   // cols tc + 32*j
    const int tr = t >> 5;   // rows tr*8 + i
    float acc[8][8];
#pragma unroll
    for (int i = 0; i < 8; ++i)
#pragma unroll
        for (int j = 0; j < 8; ++j) acc[i][j] = 0.f;

    for (int k0 = 0; k0 < F_IN; k0 += 16) {
        // stage x: 64 rows x 16 k; thread loads float4 along k
        {
            int r = t >> 2;
            int kk = (t & 3) * 4;
            int gr = row0 + r;
            float4 v = make_float4(0.f, 0.f, 0.f, 0.f);
            if (gr < N) v = *(const float4*)(x + (size_t)gr * F_IN + k0 + kk);
            xs[kk + 0][r] = v.x; xs[kk + 1][r] = v.y;
            xs[kk + 2][r] = v.z; xs[kk + 3][r] = v.w;
        }
        // stage W: 16x256 floats = 1024 float4
#pragma unroll
        for (int j = 0; j < 4; ++j) {
            int idx = t + j * 256;
            ((float4*)wsm)[idx] = ((const float4*)(W + (size_t)k0 * C1))[idx];
        }
        __syncthreads();
#pragma unroll
        for (int k = 0; k < 16; ++k) {
            float xv[8], wv[8];
#pragma unroll
            for (int i = 0; i < 8; ++i) xv[i] = xs[k][tr * 8 + i];
#pragma unroll
            for (int j = 0; j < 8; ++j) wv[j] = wsm[k][tc + 32 * j];
#pragma unroll
            for (int i = 0; i < 8; ++i)
#pragma unroll
                for (int j = 0; j < 8; ++j) acc[i][j] += xv[i] * wv[j];
        }
        __syncthreads();
    }
#pragma unroll
    for (int i = 0; i < 8; ++i) {
        int gr = row0 + tr * 8 + i;
        if (gr < N) {
#pragma unroll
            for (int j = 0; j < 8; ++j)
                h[(size_t)gr * C1 + tc + 32 * j] = acc[i][j];
        }
    }
}

// ------------- K1b: attention coefficients a_src/a_dst [N,8] ---------------
// one wave per node; lane l owns channels 4l..4l+3 (head = l>>3)
__global__ __launch_bounds__(256) void attcoef1_k(const float* __restrict__ h,
                                                  const float* __restrict__ att_s,
                                                  const float* __restrict__ att_d,
                                                  float* __restrict__ asrc,
                                                  float* __restrict__ adst, int N) {
    const int lane = threadIdx.x & 63;
    const int n = blockIdx.x * 4 + (threadIdx.x >> 6);
    if (n >= N) return;
    float4 hv = *(const float4*)(h + (size_t)n * C1 + lane * 4);
    const int hd = lane >> 3;
    float4 as = *(const float4*)(att_s + hd * 32 + (lane & 7) * 4);
    float4 ad = *(const float4*)(att_d + hd * 32 + (lane & 7) * 4);
    float ps = hv.x * as.x + hv.y * as.y + hv.z * as.z + hv.w * as.w;
    float pd = hv.x * ad.x + hv.y * ad.y + hv.z * ad.z + hv.w * ad.w;
#pragma unroll
    for (int off = 1; off < 8; off <<= 1) {
        ps += __shfl_xor(ps, off);
        pd += __shfl_xor(pd, off);
    }
    if ((lane & 7) == 0) {
        asrc[n * 8 + hd] = ps;
        adst[n * 8 + hd] = pd;
    }
}

// ---------------- K2a: histogram of dst (int atomics) ----------------------
__global__ void hist_k(const int* __restrict__ ei, int* __restrict__ counts,
                       int E, int N) {
    int i = blockIdx.x * 256 + threadIdx.x;
    int tot = E + N;
    if (i >= tot) return;
    int d = (i < E) ? ei[E + i] : (i - E);
    atomicAdd(&counts[d], 1);
}

// ---------------- K2b: single-block exclusive scan -> rowptr, cursor -------
__global__ __launch_bounds__(1024) void scan_k(const int* __restrict__ counts,
                                               int* __restrict__ rowptr,
                                               int* __restrict__ cursor, int N) {
    __shared__ int part[1024];
    const int t = threadIdx.x;
    const int CH = (N + 1023) / 1024;
    int b = t * CH, e = min(b + CH, N);
    int s = 0;
    for (int i = b; i < e; ++i) s += counts[i];
    part[t] = s;
    __syncthreads();
    for (int off = 1; off < 1024; off <<= 1) {
        int v = (t >= off) ? part[t - off] : 0;
        __syncthreads();
        part[t] += v;
        __syncthreads();
    }
    int base = (t == 0) ? 0 : part[t - 1];
    int run = base;
    for (int i = b; i < e; ++i) {
        rowptr[i] = run;
        cursor[i] = run;
        run += counts[i];
    }
    if (t == 1023) rowptr[N] = run;
}

// ---------------- K2c: scatter edges into CSR ------------------------------
__global__ void scatter_k(const int* __restrict__ ei, int* __restrict__ cursor,
                          int* __restrict__ ssrc, int E, int N) {
    int i = blockIdx.x * 256 + threadIdx.x;
    int tot = E + N;
    if (i >= tot) return;
    int s, d;
    if (i < E) { s = ei[i]; d = ei[E + i]; }
    else       { s = i - E; d = s; }
    int pos = atomicAdd(&cursor[d], 1);
    ssrc[pos] = s;
}

// ------- K3: fused layer-1 softmax-aggregate + bias + ReLU + layer-2 -------
// one wave per node. lane l: channels 4l..4l+3, head = l>>3.
__global__ __launch_bounds__(256) void agg1_k(const float* __restrict__ h,
                                              const float* __restrict__ asrc,
                                              const float* __restrict__ adst,
                                              const int* __restrict__ rowptr,
                                              const int* __restrict__ ssrc,
                                              const float* __restrict__ b1,
                                              const float* __restrict__ W2,
                                              const float* __restrict__ as2,
                                              const float* __restrict__ ad2,
                                              float4* __restrict__ tab2, int N) {
    const int lane = threadIdx.x & 63;
    const int n = blockIdx.x * 4 + (threadIdx.x >> 6);
    if (n >= N) return;
    const int hd = lane >> 3;
    const float adn = adst[n * 8 + hd];
    const int beg = rowptr[n], end = rowptr[n + 1];

    float m = -1e30f;
    for (int j = beg; j < end; ++j) {
        int s = ssrc[j];
        float a = asrc[s * 8 + hd] + adn;
        a = (a > 0.f) ? a : NEG * a;
        m = fmaxf(m, a);
    }
    float ssum = 0.f;
    float4 acc = make_float4(0.f, 0.f, 0.f, 0.f);
    for (int j = beg; j < end; ++j) {
        int s = ssrc[j];
        float a = asrc[s * 8 + hd] + adn;
        a = (a > 0.f) ? a : NEG * a;
        float ev = __expf(a - m);
        ssum += ev;
        float4 hv = *(const float4*)(h + (size_t)s * C1 + lane * 4);
        acc.x += hv.x * ev; acc.y += hv.y * ev;
        acc.z += hv.z * ev; acc.w += hv.w * ev;
    }
    const float inv = 1.f / ssum;  // self-loop guarantees ssum >= 1
    float4 bv = *(const float4*)(b1 + lane * 4);
    float o0 = fmaxf(acc.x * inv + bv.x, 0.f);
    float o1 = fmaxf(acc.y * inv + bv.y, 0.f);
    float o2 = fmaxf(acc.z * inv + bv.z, 0.f);
    float o3 = fmaxf(acc.w * inv + bv.w, 0.f);

    // layer-2 projection: W2 [256,2] row-major; rows 4l..4l+3 = 8 floats
    float4 w20 = *(const float4*)(W2 + lane * 8);      // (r,j0),(r,j1),(r+1,j0),(r+1,j1)
    float4 w21 = *(const float4*)(W2 + lane * 8 + 4);
    float p0 = o0 * w20.x + o1 * w20.z + o2 * w21.x + o3 * w21.z;
    float p1 = o0 * w20.y + o1 * w20.w + o2 * w21.y + o3 * w21.w;
#pragma unroll
    for (int off = 1; off < 64; off <<= 1) {
        p0 += __shfl_xor(p0, off);
        p1 += __shfl_xor(p1, off);
    }
    if (lane == 0) {
        float a2s = p0 * as2[0] + p1 * as2[1];
        float a2d = p0 * ad2[0] + p1 * ad2[1];
        tab2[n] = make_float4(p0, p1, a2s, a2d);
    }
}

// ---------------- K4: layer-2 aggregation (1 thread / node) ----------------
__global__ void agg2_k(const int* __restrict__ rowptr, const int* __restrict__ ssrc,
                       const float4* __restrict__ tab2, const float* __restrict__ b2,
                       float* __restrict__ out, int N) {
    int n = blockIdx.x * 256 + threadIdx.x;
    if (n >= N) return;
    const float a2d = tab2[n].w;
    const int beg = rowptr[n], end = rowptr[n + 1];
    float m = -1e30f;
    for (int j = beg; j < end; ++j) {
        float a = tab2[ssrc[j]].z + a2d;
        a = (a > 0.f) ? a : NEG * a;
        m = fmaxf(m, a);
    }
    float ssum = 0.f, a0 = 0.f, a1 = 0.f;
    for (int j = beg; j < end; ++j) {
        float4 tv = tab2[ssrc[j]];
        float a = tv.z + a2d;
        a = (a > 0.f) ? a : NEG * a;
        float ev = __expf(a - m);
        ssum += ev;
        a0 += tv.x * ev;
        a1 += tv.y * ev;
    }
    float inv = 1.f / ssum;
    out[(size_t)n * 2 + 0] = a0 * inv + b2[0];
    out[(size_t)n * 2 + 1] = a1 * inv + b2[1];
}

// ---------------------------------------------------------------------------
extern "C" void kernel_launch(void* const* d_in, const int* in_sizes, int n_in,
                              void* d_out, int out_size, void* d_ws, size_t ws_size,
                              hipStream_t stream) {
    const float* x   = (const float*)d_in[0];
    const int*   ei  = (const int*)d_in[1];
    const float* W1  = (const float*)d_in[2];
    const float* at_s1 = (const float*)d_in[3];
    const float* at_d1 = (const float*)d_in[4];
    const float* b1  = (const float*)d_in[5];
    const float* W2  = (const float*)d_in[6];
    const float* at_s2 = (const float*)d_in[7];
    const float* at_d2 = (const float*)d_in[8];
    const float* b2  = (const float*)d_in[9];
    float* out = (float*)d_out;

    const int N = in_sizes[0] / F_IN;  // 50000
    const int E = in_sizes[1] / 2;     // 800000
    const int TOT = E + N;

    char* ws = (char*)d_ws;
    size_t off = 0;
    auto alloc = [&](size_t bytes) -> void* {
        void* p = ws + off;
        off = (off + bytes + 255) & ~(size_t)255;
        return p;
    };
    float*  h      = (float*)alloc((size_t)N * C1 * 4);
    float*  asrc   = (float*)alloc((size_t)N * 8 * 4);
    float*  adst   = (float*)alloc((size_t)N * 8 * 4);
    int*    counts = (int*)alloc((size_t)N * 4);
    int*    rowptr = (int*)alloc((size_t)(N + 1) * 4);
    int*    cursor = (int*)alloc((size_t)N * 4);
    int*    ssrc   = (int*)alloc((size_t)TOT * 4);
    float4* tab2   = (float4*)alloc((size_t)N * 16);

    hipMemsetAsync(counts, 0, (size_t)N * 4, stream);

    gemm1_k<<<(N + 63) / 64, 256, 0, stream>>>(x, W1, h, N);
    attcoef1_k<<<(N + 3) / 4, 256, 0, stream>>>(h, at_s1, at_d1, asrc, adst, N);
    hist_k<<<(TOT + 255) / 256, 256, 0, stream>>>(ei, counts, E, N);
    scan_k<<<1, 1024, 0, stream>>>(counts, rowptr, cursor, N);
    scatter_k<<<(TOT + 255) / 256, 256, 0, stream>>>(ei, cursor, ssrc, E, N);
    agg1_k<<<(N + 3) / 4, 256, 0, stream>>>(h, asrc, adst, rowptr, ssrc,
                                            b1, W2, at_s2, at_d2, tab2, N);
    agg2_k<<<(N + 255) / 256, 256, 0, stream>>>(rowptr, ssrc, tab2, b2, out, N);
}

// Round 2
// 327.780 us; speedup vs baseline: 1.3846x; 1.3846x over previous
//
#include <hip/hip_runtime.h>

#define F_IN 128
#define C1 256
#define NEG 0.2f

__global__ __launch_bounds__(256) void gemm1_k(const float* __restrict__ x,
                                               const float* __restrict__ W,
                                               float* __restrict__ h, int N) {
    __shared__ float xs[16][64];
    __shared__ float wsm[16][256];
    const int t = threadIdx.x;
    const int row0 = blockIdx.x * 64;
    const int tc = t & 31;
    const int tr = t >> 5;
    float acc[8][8];
#pragma unroll
    for (int i = 0; i < 8; ++i)
#pragma unroll
        for (int j = 0; j < 8; ++j) acc[i][j] = 0.f;

    for (int k0 = 0; k0 < F_IN; k0 += 16) {
        {
            int r = t >> 2;
            int kk = (t & 3) * 4;
            int gr = row0 + r;
            float4 v = make_float4(0.f, 0.f, 0.f, 0.f);
            if (gr < N) v = *(const float4*)(x + (size_t)gr * F_IN + k0 + kk);
            xs[kk + 0][r] = v.x; xs[kk + 1][r] = v.y;
            xs[kk + 2][r] = v.z; xs[kk + 3][r] = v.w;
        }
#pragma unroll
        for (int j = 0; j < 4; ++j) {
            int idx = t + j * 256;
            ((float4*)wsm)[idx] = ((const float4*)(W + (size_t)k0 * C1))[idx];
        }
        __syncthreads();
#pragma unroll
        for (int k = 0; k < 16; ++k) {
            float xv[8], wv[8];
#pragma unroll
            for (int i = 0; i < 8; ++i) xv[i] = xs[k][tr * 8 + i];
#pragma unroll
            for (int j = 0; j < 8; ++j) wv[j] = wsm[k][tc + 32 * j];
#pragma unroll
            for (int i = 0; i < 8; ++i)
#pragma unroll
                for (int j = 0; j < 8; ++j) acc[i][j] += xv[i] * wv[j];
        }
        __syncthreads();
    }
#pragma unroll
    for (int i = 0; i < 8; ++i) {
        int gr = row0 + tr * 8 + i;
        if (gr < N) {
#pragma unroll
            for (int j = 0; j < 8; ++j)
                h[(size_t)gr * C1 + tc + 32 * j] = acc[i][j];
        }
    }
}

__global__ __launch_bounds__(256) void attcoef1_k(const float* __restrict__ h,
                                                  const float* __restrict__ att_s,
                                                  const float* __restrict__ att_d,
                                                  float* __restrict__ asrc,
                                                  float* __restrict__ adst, int N) {
    const int lane = threadIdx.x & 63;
    const int n = blockIdx.x * 4 + (threadIdx.x >> 6);
    if (n >= N) return;
    float4 hv = *(const float4*)(h + (size_t)n * C1 + lane * 4);
    const int hd = lane >> 3;
    float4 as = *(const float4*)(att_s + hd * 32 + (lane & 7) * 4);
    float4 ad = *(const float4*)(att_d + hd * 32 + (lane & 7) * 4);
    float ps = hv.x * as.x + hv.y * as.y + hv.z * as.z + hv.w * as.w;
    float pd = hv.x * ad.x + hv.y * ad.y + hv.z * ad.z + hv.w * ad.w;
#pragma unroll
    for (int off = 1; off < 8; off <<= 1) {
        ps += __shfl_xor(ps, off);
        pd += __shfl_xor(pd, off);
    }
    if ((lane & 7) == 0) {
        asrc[n * 8 + hd] = ps;
        adst[n * 8 + hd] = pd;
    }
}

__global__ void hist_k(const int* __restrict__ ei, int* __restrict__ counts,
                       int E, int N) {
    int i = blockIdx.x * 256 + threadIdx.x;
    int tot = E + N;
    if (i >= tot) return;
    int d = (i < E) ? ei[E + i] : (i - E);
    atomicAdd(&counts[d], 1);
}

__global__ __launch_bounds__(1024) void scan_k(const int* __restrict__ counts,
                                               int* __restrict__ rowptr,
                                               int* __restrict__ cursor, int N) {
    __shared__ int wsum[16];
    const int t = threadIdx.x;
    const int lane = t & 63;
    const int wid = t >> 6;
    const int CH = ((N + 1023) / 1024 + 3) & ~3;
    const int b = t * CH;
    const int e = min(b + CH, N);
    int s = 0;
    int i = b;
    for (; i + 4 <= e; i += 4) {
        int4 v = *(const int4*)(counts + i);
        s += v.x + v.y + v.z + v.w;
    }
    for (; i < e; ++i) s += counts[i];

    int v = s;
#pragma unroll
    for (int off = 1; off < 64; off <<= 1) {
        int u = __shfl_up(v, off);
        if (lane >= off) v += u;
    }
    if (lane == 63) wsum[wid] = v;
    __syncthreads();
    if (t < 16) {
        int w = wsum[t];
#pragma unroll
        for (int off = 1; off < 16; off <<= 1) {
            int u = __shfl_up(w, off);
            if (t >= off) w += u;
        }
        wsum[t] = w;
    }
    __syncthreads();
    int run = v - s + ((wid > 0) ? wsum[wid - 1] : 0);
    i = b;
    for (; i + 4 <= e; i += 4) {
        int4 c = *(const int4*)(counts + i);
        int4 w;
        w.x = run;
        w.y = w.x + c.x;
        w.z = w.y + c.y;
        w.w = w.z + c.z;
        run = w.w + c.w;
        *(int4*)(rowptr + i) = w;
        *(int4*)(cursor + i) = w;
    }
    for (; i < e; ++i) {
        rowptr[i] = run;
        cursor[i] = run;
        run += counts[i];
    }
    if (t == 1023) rowptr[N] = wsum[15];
}

__global__ void scatter_k(const int* __restrict__ ei, int* __restrict__ cursor,
                          int* __restrict__ ssrc, int E, int N) {
    int i = blockIdx.x * 256 + threadIdx.x;
    int tot = E + N;
    if (i >= tot) return;
    int s, d;
    if (i < E) { s = ei[i]; d = ei[E + i]; }
    else       { s = i - E; d = s; }
    int pos = atomicAdd(&cursor[d], 1);
    ssrc[pos] = s;
}

__global__ __launch_bounds__(256) void agg1_k(const float* __restrict__ h,
                                              const float* __restrict__ asrc,
                                              const float* __restrict__ adst,
                                              const int* __restrict__ rowptr,
                                              const int* __restrict__ ssrc,
                                              const float* __restrict__ b1,
                                              const float* __restrict__ W2,
                                              const float* __restrict__ as2,
                                              const float* __restrict__ ad2,
                                              float4* __restrict__ tab2, int N) {
    const int lane = threadIdx.x & 63;
    const int n = blockIdx.x * 4 + (threadIdx.x >> 6);
    if (n >= N) return;
    const int hd = lane >> 3;
    const float adn = adst[n * 8 + hd];
    const int beg = rowptr[n], end = rowptr[n + 1];

    float m = -1e30f, ssum = 0.f;
    float4 acc = make_float4(0.f, 0.f, 0.f, 0.f);
    int j = beg;
    for (; j + 1 < end; j += 2) {
        int s0 = ssrc[j], s1 = ssrc[j + 1];
        float4 h0 = *(const float4*)(h + (size_t)s0 * C1 + lane * 4);
        float4 h1 = *(const float4*)(h + (size_t)s1 * C1 + lane * 4);
        float a0 = asrc[s0 * 8 + hd] + adn;
        a0 = (a0 > 0.f) ? a0 : NEG * a0;
        float a1 = asrc[s1 * 8 + hd] + adn;
        a1 = (a1 > 0.f) ? a1 : NEG * a1;
        float mn = fmaxf(m, fmaxf(a0, a1));
        float c = __expf(m - mn);
        float e0 = __expf(a0 - mn);
        float e1 = __expf(a1 - mn);
        ssum = ssum * c + e0 + e1;
        acc.x = acc.x * c + h0.x * e0 + h1.x * e1;
        acc.y = acc.y * c + h0.y * e0 + h1.y * e1;
        acc.z = acc.z * c + h0.z * e0 + h1.z * e1;
        acc.w = acc.w * c + h0.w * e0 + h1.w * e1;
        m = mn;
    }
    if (j < end) {
        int s0 = ssrc[j];
        float4 h0 = *(const float4*)(h + (size_t)s0 * C1 + lane * 4);
        float a0 = asrc[s0 * 8 + hd] + adn;
        a0 = (a0 > 0.f) ? a0 : NEG * a0;
        float mn = fmaxf(m, a0);
        float c = __expf(m - mn);
        float e0 = __expf(a0 - mn);
        ssum = ssum * c + e0;
        acc.x = acc.x * c + h0.x * e0;
        acc.y = acc.y * c + h0.y * e0;
        acc.z = acc.z * c + h0.z * e0;
        acc.w = acc.w * c + h0.w * e0;
    }

    const float inv = 1.f / ssum;
    float4 bv = *(const float4*)(b1 + lane * 4);
    float o0 = fmaxf(acc.x * inv + bv.x, 0.f);
    float o1 = fmaxf(acc.y * inv + bv.y, 0.f);
    float o2 = fmaxf(acc.z * inv + bv.z, 0.f);
    float o3 = fmaxf(acc.w * inv + bv.w, 0.f);

    float4 w20 = *(const float4*)(W2 + lane * 8);
    float4 w21 = *(const float4*)(W2 + lane * 8 + 4);
    float p0 = o0 * w20.x + o1 * w20.z + o2 * w21.x + o3 * w21.z;
    float p1 = o0 * w20.y + o1 * w20.w + o2 * w21.y + o3 * w21.w;
#pragma unroll
    for (int off = 1; off < 64; off <<= 1) {
        p0 += __shfl_xor(p0, off);
        p1 += __shfl_xor(p1, off);
    }
    if (lane == 0) {
        float a2s = p0 * as2[0] + p1 * as2[1];
        float a2d = p0 * ad2[0] + p1 * ad2[1];
        tab2[n] = make_float4(p0, p1, a2s, a2d);
    }
}

__global__ __launch_bounds__(256) void agg2_k(const int* __restrict__ rowptr,
                                              const int* __restrict__ ssrc,
                                              const float4* __restrict__ tab2,
                                              const float* __restrict__ b2,
                                              float* __restrict__ out, int N) {
    const int t = threadIdx.x;
    const int sub = t & 7;
    const int n = blockIdx.x * 32 + (t >> 3);
    if (n >= N) return;
    const float a2d = tab2[n].w;
    const int beg = rowptr[n], end = rowptr[n + 1];
    float m = -1e30f, ssum = 0.f, a0 = 0.f, a1 = 0.f;
    for (int j = beg + sub; j < end; j += 8) {
        float4 tv = tab2[ssrc[j]];
        float a = tv.z + a2d;
        a = (a > 0.f) ? a : NEG * a;
        float mn = fmaxf(m, a);
        float c = __expf(m - mn);
        float ev = __expf(a - mn);
        ssum = ssum * c + ev;
        a0 = a0 * c + tv.x * ev;
        a1 = a1 * c + tv.y * ev;
        m = mn;
    }
#pragma unroll
    for (int off = 1; off < 8; off <<= 1) {
        float mo = __shfl_xor(m, off);
        float so = __shfl_xor(ssum, off);
        float x0 = __shfl_xor(a0, off);
        float x1 = __shfl_xor(a1, off);
        float mn = fmaxf(m, mo);
        float c = __expf(m - mn), co = __expf(mo - mn);
        ssum = ssum * c + so * co;
        a0 = a0 * c + x0 * co;
        a1 = a1 * c + x1 * co;
        m = mn;
    }
    if (sub == 0) {
        float inv = 1.f / ssum;
        out[(size_t)n * 2 + 0] = a0 * inv + b2[0];
        out[(size_t)n * 2 + 1] = a1 * inv + b2[1];
    }
}

extern "C" void kernel_launch(void* const* d_in, const int* in_sizes, int n_in,
                              void* d_out, int out_size, void* d_ws, size_t ws_size,
                              hipStream_t stream) {
    const float* x   = (const float*)d_in[0];
    const int*   ei  = (const int*)d_in[1];
    const float* W1  = (const float*)d_in[2];
    const float* at_s1 = (const float*)d_in[3];
    const float* at_d1 = (const float*)d_in[4];
    const float* b1  = (const float*)d_in[5];
    const float* W2  = (const float*)d_in[6];
    const float* at_s2 = (const float*)d_in[7];
    const float* at_d2 = (const float*)d_in[8];
    const float* b2  = (const float*)d_in[9];
    float* out = (float*)d_out;

    const int N = in_sizes[0] / F_IN;
    const int E = in_sizes[1] / 2;
    const int TOT = E + N;

    char* ws = (char*)d_ws;
    size_t off = 0;
    auto alloc = [&](size_t bytes) -> void* {
        void* p = ws + off;
        off = (off + bytes + 255) & ~(size_t)255;
        return p;
    };
    float*  h      = (float*)alloc((size_t)N * C1 * 4);
    float*  asrc   = (float*)alloc((size_t)N * 8 * 4);
    float*  adst   = (float*)alloc((size_t)N * 8 * 4);
    int*    counts = (int*)alloc((size_t)N * 4);
    int*    rowptr = (int*)alloc((size_t)(N + 1) * 4);
    int*    cursor = (int*)alloc((size_t)N * 4);
    int*    ssrc   = (int*)alloc((size_t)TOT * 4);
    float4* tab2   = (float4*)alloc((size_t)N * 16);

    hipMemsetAsync(counts, 0, (size_t)N * 4, stream);

    gemm1_k<<<(N + 63) / 64, 256, 0, stream>>>(x, W1, h, N);
    attcoef1_k<<<(N + 3) / 4, 256, 0, stream>>>(h, at_s1, at_d1, asrc, adst, N);
    hist_k<<<(TOT + 255) / 256, 256, 0, stream>>>(ei, counts, E, N);
    scan_k<<<1, 1024, 0, stream>>>(counts, rowptr, cursor, N);
    scatter_k<<<(TOT + 255) / 256, 256, 0, stream>>>(ei, cursor, ssrc, E, N);
    agg1_k<<<(N + 3) / 4, 256, 0, stream>>>(h, asrc, adst, rowptr, ssrc,
                                            b1, W2, at_s2, at_d2, tab2, N);
    agg2_k<<<(N + 31) / 32, 256, 0, stream>>>(rowptr, ssrc, tab2, b2, out, N);
}

// Round 3
// 270.976 us; speedup vs baseline: 1.6749x; 1.2096x over previous
//
#include <hip/hip_runtime.h>
#include <hip/hip_fp16.h>

#define F_IN 128
#define C1 256
#define NEG 0.2f

// ---------------- K1: x[N,128] @ W1[128,256] -> h_fp16[N,256] --------------
__global__ __launch_bounds__(256) void gemm1_k(const float* __restrict__ x,
                                               const float* __restrict__ W,
                                               __half* __restrict__ hh, int N) {
    __shared__ float xs[16][64];
    __shared__ float wsm[16][256];
    const int t = threadIdx.x;
    const int row0 = blockIdx.x * 64;
    const int tc = t & 31;
    const int tr = t >> 5;
    float acc[8][8];
#pragma unroll
    for (int i = 0; i < 8; ++i)
#pragma unroll
        for (int j = 0; j < 8; ++j) acc[i][j] = 0.f;

    for (int k0 = 0; k0 < F_IN; k0 += 16) {
        {
            int r = t >> 2;
            int kk = (t & 3) * 4;
            int gr = row0 + r;
            float4 v = make_float4(0.f, 0.f, 0.f, 0.f);
            if (gr < N) v = *(const float4*)(x + (size_t)gr * F_IN + k0 + kk);
            xs[kk + 0][r] = v.x; xs[kk + 1][r] = v.y;
            xs[kk + 2][r] = v.z; xs[kk + 3][r] = v.w;
        }
#pragma unroll
        for (int j = 0; j < 4; ++j) {
            int idx = t + j * 256;
            ((float4*)wsm)[idx] = ((const float4*)(W + (size_t)k0 * C1))[idx];
        }
        __syncthreads();
#pragma unroll
        for (int k = 0; k < 16; ++k) {
            float xv[8], wv[8];
#pragma unroll
            for (int i = 0; i < 8; ++i) xv[i] = xs[k][tr * 8 + i];
#pragma unroll
            for (int j = 0; j < 8; ++j) wv[j] = wsm[k][tc + 32 * j];
#pragma unroll
            for (int i = 0; i < 8; ++i)
#pragma unroll
                for (int j = 0; j < 8; ++j) acc[i][j] += xv[i] * wv[j];
        }
        __syncthreads();
    }
#pragma unroll
    for (int i = 0; i < 8; ++i) {
        int gr = row0 + tr * 8 + i;
        if (gr < N) {
#pragma unroll
            for (int j = 0; j < 8; ++j)
                hh[(size_t)gr * C1 + tc + 32 * j] = __float2half_rn(acc[i][j]);
        }
    }
}

// ------------- K1b: attention coefficients a_src/a_dst [N,8] ---------------
__global__ __launch_bounds__(256) void attcoef1_k(const __half* __restrict__ hh,
                                                  const float* __restrict__ att_s,
                                                  const float* __restrict__ att_d,
                                                  float* __restrict__ asrc,
                                                  float* __restrict__ adst, int N) {
    const int lane = threadIdx.x & 63;
    const int n = blockIdx.x * 4 + (threadIdx.x >> 6);
    if (n >= N) return;
    float2 raw = *(const float2*)(hh + (size_t)n * C1 + lane * 4);
    const __half2* ph = (const __half2*)&raw;
    float2 f0 = __half22float2(ph[0]);
    float2 f1 = __half22float2(ph[1]);
    const int hd = lane >> 3;
    float4 as = *(const float4*)(att_s + hd * 32 + (lane & 7) * 4);
    float4 ad = *(const float4*)(att_d + hd * 32 + (lane & 7) * 4);
    float ps = f0.x * as.x + f0.y * as.y + f1.x * as.z + f1.y * as.w;
    float pd = f0.x * ad.x + f0.y * ad.y + f1.x * ad.z + f1.y * ad.w;
#pragma unroll
    for (int off = 1; off < 8; off <<= 1) {
        ps += __shfl_xor(ps, off);
        pd += __shfl_xor(pd, off);
    }
    if ((lane & 7) == 0) {
        asrc[n * 8 + hd] = ps;
        adst[n * 8 + hd] = pd;
    }
}

// ---------------- K2a: histogram of dst ------------------------------------
__global__ void hist_k(const int* __restrict__ ei, int* __restrict__ counts,
                       int E, int N) {
    int i = blockIdx.x * 256 + threadIdx.x;
    int tot = E + N;
    if (i >= tot) return;
    int d = (i < E) ? ei[E + i] : (i - E);
    atomicAdd(&counts[d], 1);
}

// ---------------- K2b: single-block scan -> rowptr, cursor -----------------
__global__ __launch_bounds__(1024) void scan_k(const int* __restrict__ counts,
                                               int* __restrict__ rowptr,
                                               int* __restrict__ cursor, int N) {
    __shared__ int wsum[16];
    const int t = threadIdx.x;
    const int lane = t & 63;
    const int wid = t >> 6;
    const int CH = ((N + 1023) / 1024 + 3) & ~3;
    const int b = t * CH;
    const int e = min(b + CH, N);
    int s = 0;
    int i = b;
    for (; i + 4 <= e; i += 4) {
        int4 v = *(const int4*)(counts + i);
        s += v.x + v.y + v.z + v.w;
    }
    for (; i < e; ++i) s += counts[i];

    int v = s;
#pragma unroll
    for (int off = 1; off < 64; off <<= 1) {
        int u = __shfl_up(v, off);
        if (lane >= off) v += u;
    }
    if (lane == 63) wsum[wid] = v;
    __syncthreads();
    if (t < 16) {
        int w = wsum[t];
#pragma unroll
        for (int off = 1; off < 16; off <<= 1) {
            int u = __shfl_up(w, off);
            if (t >= off) w += u;
        }
        wsum[t] = w;
    }
    __syncthreads();
    int run = v - s + ((wid > 0) ? wsum[wid - 1] : 0);
    i = b;
    for (; i + 4 <= e; i += 4) {
        int4 c = *(const int4*)(counts + i);
        int4 w;
        w.x = run;
        w.y = w.x + c.x;
        w.z = w.y + c.y;
        w.w = w.z + c.z;
        run = w.w + c.w;
        *(int4*)(rowptr + i) = w;
        *(int4*)(cursor + i) = w;
    }
    for (; i < e; ++i) {
        rowptr[i] = run;
        cursor[i] = run;
        run += counts[i];
    }
    if (t == 1023) rowptr[N] = wsum[15];
}

// ---------------- K2c: scatter edges into CSR ------------------------------
__global__ void scatter_k(const int* __restrict__ ei, int* __restrict__ cursor,
                          int* __restrict__ ssrc, int E, int N) {
    int i = blockIdx.x * 256 + threadIdx.x;
    int tot = E + N;
    if (i >= tot) return;
    int s, d;
    if (i < E) { s = ei[i]; d = ei[E + i]; }
    else       { s = i - E; d = s; }
    int pos = atomicAdd(&cursor[d], 1);
    ssrc[pos] = s;
}

// ------- K3: fused layer-1 softmax-aggregate + bias + ReLU + layer-2 -------
// one wave per node, single-pass online softmax, 4-edge unroll, fp16 h.
__global__ __launch_bounds__(256) void agg1_k(const __half* __restrict__ hh,
                                              const float* __restrict__ asrc,
                                              const float* __restrict__ adst,
                                              const int* __restrict__ rowptr,
                                              const int* __restrict__ ssrc,
                                              const float* __restrict__ b1,
                                              const float* __restrict__ W2,
                                              const float* __restrict__ as2,
                                              const float* __restrict__ ad2,
                                              float4* __restrict__ tab2, int N) {
    const int lane = threadIdx.x & 63;
    const int n = blockIdx.x * 4 + (threadIdx.x >> 6);
    if (n >= N) return;
    const int hd = lane >> 3;
    const float adn = adst[n * 8 + hd];
    const int beg = rowptr[n], end = rowptr[n + 1];
    const size_t loff = lane * 4;

    float m = -1e30f, ssum = 0.f;
    float4 acc = make_float4(0.f, 0.f, 0.f, 0.f);
    int j = beg;
    for (; j + 3 < end; j += 4) {
        int s0 = ssrc[j], s1 = ssrc[j + 1], s2 = ssrc[j + 2], s3 = ssrc[j + 3];
        float2 r0 = *(const float2*)(hh + (size_t)s0 * C1 + loff);
        float2 r1 = *(const float2*)(hh + (size_t)s1 * C1 + loff);
        float2 r2 = *(const float2*)(hh + (size_t)s2 * C1 + loff);
        float2 r3 = *(const float2*)(hh + (size_t)s3 * C1 + loff);
        float a0 = asrc[s0 * 8 + hd] + adn; a0 = (a0 > 0.f) ? a0 : NEG * a0;
        float a1 = asrc[s1 * 8 + hd] + adn; a1 = (a1 > 0.f) ? a1 : NEG * a1;
        float a2 = asrc[s2 * 8 + hd] + adn; a2 = (a2 > 0.f) ? a2 : NEG * a2;
        float a3 = asrc[s3 * 8 + hd] + adn; a3 = (a3 > 0.f) ? a3 : NEG * a3;
        float mn = fmaxf(fmaxf(fmaxf(a0, a1), fmaxf(a2, a3)), m);
        float c = __expf(m - mn);
        float e0 = __expf(a0 - mn), e1 = __expf(a1 - mn);
        float e2 = __expf(a2 - mn), e3 = __expf(a3 - mn);
        ssum = ssum * c + e0 + e1 + e2 + e3;
        const __half2* p0 = (const __half2*)&r0;
        const __half2* p1 = (const __half2*)&r1;
        const __half2* p2 = (const __half2*)&r2;
        const __half2* p3 = (const __half2*)&r3;
        float2 f0a = __half22float2(p0[0]), f0b = __half22float2(p0[1]);
        float2 f1a = __half22float2(p1[0]), f1b = __half22float2(p1[1]);
        float2 f2a = __half22float2(p2[0]), f2b = __half22float2(p2[1]);
        float2 f3a = __half22float2(p3[0]), f3b = __half22float2(p3[1]);
        acc.x = acc.x * c + f0a.x * e0 + f1a.x * e1 + f2a.x * e2 + f3a.x * e3;
        acc.y = acc.y * c + f0a.y * e0 + f1a.y * e1 + f2a.y * e2 + f3a.y * e3;
        acc.z = acc.z * c + f0b.x * e0 + f1b.x * e1 + f2b.x * e2 + f3b.x * e3;
        acc.w = acc.w * c + f0b.y * e0 + f1b.y * e1 + f2b.y * e2 + f3b.y * e3;
        m = mn;
    }
    for (; j < end; ++j) {
        int s0 = ssrc[j];
        float2 r0 = *(const float2*)(hh + (size_t)s0 * C1 + loff);
        float a0 = asrc[s0 * 8 + hd] + adn; a0 = (a0 > 0.f) ? a0 : NEG * a0;
        float mn = fmaxf(m, a0);
        float c = __expf(m - mn);
        float e0 = __expf(a0 - mn);
        const __half2* p0 = (const __half2*)&r0;
        float2 f0a = __half22float2(p0[0]), f0b = __half22float2(p0[1]);
        ssum = ssum * c + e0;
        acc.x = acc.x * c + f0a.x * e0;
        acc.y = acc.y * c + f0a.y * e0;
        acc.z = acc.z * c + f0b.x * e0;
        acc.w = acc.w * c + f0b.y * e0;
        m = mn;
    }

    const float inv = 1.f / ssum;
    float4 bv = *(const float4*)(b1 + lane * 4);
    float o0 = fmaxf(acc.x * inv + bv.x, 0.f);
    float o1 = fmaxf(acc.y * inv + bv.y, 0.f);
    float o2 = fmaxf(acc.z * inv + bv.z, 0.f);
    float o3 = fmaxf(acc.w * inv + bv.w, 0.f);

    float4 w20 = *(const float4*)(W2 + lane * 8);
    float4 w21 = *(const float4*)(W2 + lane * 8 + 4);
    float p0 = o0 * w20.x + o1 * w20.z + o2 * w21.x + o3 * w21.z;
    float p1 = o0 * w20.y + o1 * w20.w + o2 * w21.y + o3 * w21.w;
#pragma unroll
    for (int off = 1; off < 64; off <<= 1) {
        p0 += __shfl_xor(p0, off);
        p1 += __shfl_xor(p1, off);
    }
    if (lane == 0) {
        float a2s = p0 * as2[0] + p1 * as2[1];
        float a2d = p0 * ad2[0] + p1 * ad2[1];
        tab2[n] = make_float4(p0, p1, a2s, a2d);
    }
}

// ---------------- K4: layer-2 aggregation (8 lanes / node) -----------------
__global__ __launch_bounds__(256) void agg2_k(const int* __restrict__ rowptr,
                                              const int* __restrict__ ssrc,
                                              const float4* __restrict__ tab2,
                                              const float* __restrict__ b2,
                                              float* __restrict__ out, int N) {
    const int t = threadIdx.x;
    const int sub = t & 7;
    const int n = blockIdx.x * 32 + (t >> 3);
    if (n >= N) return;
    const float a2d = tab2[n].w;
    const int beg = rowptr[n], end = rowptr[n + 1];
    float m = -1e30f, ssum = 0.f, a0 = 0.f, a1 = 0.f;
    for (int j = beg + sub; j < end; j += 8) {
        float4 tv = tab2[ssrc[j]];
        float a = tv.z + a2d;
        a = (a > 0.f) ? a : NEG * a;
        float mn = fmaxf(m, a);
        float c = __expf(m - mn);
        float ev = __expf(a - mn);
        ssum = ssum * c + ev;
        a0 = a0 * c + tv.x * ev;
        a1 = a1 * c + tv.y * ev;
        m = mn;
    }
#pragma unroll
    for (int off = 1; off < 8; off <<= 1) {
        float mo = __shfl_xor(m, off);
        float so = __shfl_xor(ssum, off);
        float x0 = __shfl_xor(a0, off);
        float x1 = __shfl_xor(a1, off);
        float mn = fmaxf(m, mo);
        float c = __expf(m - mn), co = __expf(mo - mn);
        ssum = ssum * c + so * co;
        a0 = a0 * c + x0 * co;
        a1 = a1 * c + x1 * co;
        m = mn;
    }
    if (sub == 0) {
        float inv = 1.f / ssum;
        out[(size_t)n * 2 + 0] = a0 * inv + b2[0];
        out[(size_t)n * 2 + 1] = a1 * inv + b2[1];
    }
}

extern "C" void kernel_launch(void* const* d_in, const int* in_sizes, int n_in,
                              void* d_out, int out_size, void* d_ws, size_t ws_size,
                              hipStream_t stream) {
    const float* x   = (const float*)d_in[0];
    const int*   ei  = (const int*)d_in[1];
    const float* W1  = (const float*)d_in[2];
    const float* at_s1 = (const float*)d_in[3];
    const float* at_d1 = (const float*)d_in[4];
    const float* b1  = (const float*)d_in[5];
    const float* W2  = (const float*)d_in[6];
    const float* at_s2 = (const float*)d_in[7];
    const float* at_d2 = (const float*)d_in[8];
    const float* b2  = (const float*)d_in[9];
    float* out = (float*)d_out;

    const int N = in_sizes[0] / F_IN;
    const int E = in_sizes[1] / 2;
    const int TOT = E + N;

    char* ws = (char*)d_ws;
    size_t off = 0;
    auto alloc = [&](size_t bytes) -> void* {
        void* p = ws + off;
        off = (off + bytes + 255) & ~(size_t)255;
        return p;
    };
    __half* hh     = (__half*)alloc((size_t)N * C1 * 2);
    float*  asrc   = (float*)alloc((size_t)N * 8 * 4);
    float*  adst   = (float*)alloc((size_t)N * 8 * 4);
    int*    counts = (int*)alloc((size_t)N * 4);
    int*    rowptr = (int*)alloc((size_t)(N + 1) * 4);
    int*    cursor = (int*)alloc((size_t)N * 4);
    int*    ssrc   = (int*)alloc((size_t)TOT * 4);
    float4* tab2   = (float4*)alloc((size_t)N * 16);

    hipMemsetAsync(counts, 0, (size_t)N * 4, stream);

    gemm1_k<<<(N + 63) / 64, 256, 0, stream>>>(x, W1, hh, N);
    attcoef1_k<<<(N + 3) / 4, 256, 0, stream>>>(hh, at_s1, at_d1, asrc, adst, N);
    hist_k<<<(TOT + 255) / 256, 256, 0, stream>>>(ei, counts, E, N);
    scan_k<<<1, 1024, 0, stream>>>(counts, rowptr, cursor, N);
    scatter_k<<<(TOT + 255) / 256, 256, 0, stream>>>(ei, cursor, ssrc, E, N);
    agg1_k<<<(N + 3) / 4, 256, 0, stream>>>(hh, asrc, adst, rowptr, ssrc,
                                            b1, W2, at_s2, at_d2, tab2, N);
    agg2_k<<<(N + 31) / 32, 256, 0, stream>>>(rowptr, ssrc, tab2, b2, out, N);
}

// Round 4
// 247.463 us; speedup vs baseline: 1.8340x; 1.0950x over previous
//
#include <hip/hip_runtime.h>
#include <hip/hip_fp16.h>

#define F_IN 128
#define C1 256
#define NEG 0.2f

typedef _Float16 f16x8 __attribute__((ext_vector_type(8)));
typedef _Float16 f16x4 __attribute__((ext_vector_type(4)));
typedef float f32x4 __attribute__((ext_vector_type(4)));

#define XS_LD 136  // 128 + 8 f16 pad -> row stride 272 B (2-way LDS conflict = free)

// ---------------- K1: x[N,128] @ W1[128,256] -> h_fp16[N,256] via MFMA -----
// 256 thr = 4 waves; wave w owns rows w*16..w*16+15, all 256 cols.
// A (x tile) staged in LDS fp16; B (W) loaded per-lane from global (L2-hot).
__global__ __launch_bounds__(256) void gemm1_k(const float* __restrict__ x,
                                               const float* __restrict__ W,
                                               __half* __restrict__ hh, int N) {
    __shared__ _Float16 xs[64 * XS_LD];  // 17.4 KB
    const int t = threadIdx.x;
    const int row0 = blockIdx.x * 64;
    // stage x tile (f32 -> f16), coalesced: thread t -> row t>>2, cols (t&3)*32..+31
    {
        const int r = t >> 2;
        const int c0 = (t & 3) * 32;
        const int gr = row0 + r;
        _Float16* dst = xs + r * XS_LD + c0;
        if (gr < N) {
            const float4* px = (const float4*)(x + (size_t)gr * F_IN + c0);
#pragma unroll
            for (int i = 0; i < 8; ++i) {
                float4 v = px[i];
                f16x4 w;
                w[0] = (_Float16)v.x; w[1] = (_Float16)v.y;
                w[2] = (_Float16)v.z; w[3] = (_Float16)v.w;
                *(f16x4*)(dst + i * 4) = w;
            }
        } else {
            f16x4 z = {0, 0, 0, 0};
#pragma unroll
            for (int i = 0; i < 8; ++i) *(f16x4*)(dst + i * 4) = z;
        }
    }
    __syncthreads();

    const int wid = t >> 6;
    const int lane = t & 63;
    const int l15 = lane & 15;
    const int grp = lane >> 4;          // 0..3
    f32x4 acc[16];
#pragma unroll
    for (int i = 0; i < 16; ++i) acc[i] = (f32x4){0.f, 0.f, 0.f, 0.f};

    // A frag row = wid*16 + l15; k = ks*32 + grp*8 + e
    const _Float16* arow_p = xs + (wid * 16 + l15) * XS_LD;
#pragma unroll
    for (int ks = 0; ks < 4; ++ks) {
        f16x8 afr = *(const f16x8*)(arow_p + ks * 32 + grp * 8);
        const float* wbase = W + (size_t)(ks * 32 + grp * 8) * C1 + l15;
#pragma unroll
        for (int ct = 0; ct < 16; ++ct) {
            const float* wp = wbase + ct * 16;
            f16x8 bfr;
#pragma unroll
            for (int e = 0; e < 8; ++e)
                bfr[e] = (_Float16)wp[(size_t)e * C1];   // B[k][c], lanes coalesce over c
            acc[ct] = __builtin_amdgcn_mfma_f32_16x16x32_f16(afr, bfr, acc[ct], 0, 0, 0);
        }
    }
    // D: col = lane&15, row = grp*4 + reg
#pragma unroll
    for (int ct = 0; ct < 16; ++ct) {
#pragma unroll
        for (int i = 0; i < 4; ++i) {
            int gr = row0 + wid * 16 + grp * 4 + i;
            if (gr < N) hh[(size_t)gr * C1 + ct * 16 + l15] = __float2half_rn(acc[ct][i]);
        }
    }
}

// ------------- K1b: attention coefficients a_src/a_dst [N,8] ---------------
__global__ __launch_bounds__(256) void attcoef1_k(const __half* __restrict__ hh,
                                                  const float* __restrict__ att_s,
                                                  const float* __restrict__ att_d,
                                                  float* __restrict__ asrc,
                                                  float* __restrict__ adst, int N) {
    const int lane = threadIdx.x & 63;
    const int n = blockIdx.x * 4 + (threadIdx.x >> 6);
    if (n >= N) return;
    float2 raw = *(const float2*)(hh + (size_t)n * C1 + lane * 4);
    const __half2* ph = (const __half2*)&raw;
    float2 f0 = __half22float2(ph[0]);
    float2 f1 = __half22float2(ph[1]);
    const int hd = lane >> 3;
    float4 as = *(const float4*)(att_s + hd * 32 + (lane & 7) * 4);
    float4 ad = *(const float4*)(att_d + hd * 32 + (lane & 7) * 4);
    float ps = f0.x * as.x + f0.y * as.y + f1.x * as.z + f1.y * as.w;
    float pd = f0.x * ad.x + f0.y * ad.y + f1.x * ad.z + f1.y * ad.w;
#pragma unroll
    for (int off = 1; off < 8; off <<= 1) {
        ps += __shfl_xor(ps, off);
        pd += __shfl_xor(pd, off);
    }
    if ((lane & 7) == 0) {
        asrc[n * 8 + hd] = ps;
        adst[n * 8 + hd] = pd;
    }
}

// ---------------- K2a: histogram of dst ------------------------------------
__global__ void hist_k(const int* __restrict__ ei, int* __restrict__ counts,
                       int E, int N) {
    int i = blockIdx.x * 256 + threadIdx.x;
    int tot = E + N;
    if (i >= tot) return;
    int d = (i < E) ? ei[E + i] : (i - E);
    atomicAdd(&counts[d], 1);
}

// ---------------- K2b: single-block scan -> rowptr, cursor -----------------
__global__ __launch_bounds__(1024) void scan_k(const int* __restrict__ counts,
                                               int* __restrict__ rowptr,
                                               int* __restrict__ cursor, int N) {
    __shared__ int wsum[16];
    const int t = threadIdx.x;
    const int lane = t & 63;
    const int wid = t >> 6;
    const int CH = ((N + 1023) / 1024 + 3) & ~3;
    const int b = t * CH;
    const int e = min(b + CH, N);
    int s = 0;
    int i = b;
    for (; i + 4 <= e; i += 4) {
        int4 v = *(const int4*)(counts + i);
        s += v.x + v.y + v.z + v.w;
    }
    for (; i < e; ++i) s += counts[i];

    int v = s;
#pragma unroll
    for (int off = 1; off < 64; off <<= 1) {
        int u = __shfl_up(v, off);
        if (lane >= off) v += u;
    }
    if (lane == 63) wsum[wid] = v;
    __syncthreads();
    if (t < 16) {
        int w = wsum[t];
#pragma unroll
        for (int off = 1; off < 16; off <<= 1) {
            int u = __shfl_up(w, off);
            if (t >= off) w += u;
        }
        wsum[t] = w;
    }
    __syncthreads();
    int run = v - s + ((wid > 0) ? wsum[wid - 1] : 0);
    i = b;
    for (; i + 4 <= e; i += 4) {
        int4 c = *(const int4*)(counts + i);
        int4 w;
        w.x = run;
        w.y = w.x + c.x;
        w.z = w.y + c.y;
        w.w = w.z + c.z;
        run = w.w + c.w;
        *(int4*)(rowptr + i) = w;
        *(int4*)(cursor + i) = w;
    }
    for (; i < e; ++i) {
        rowptr[i] = run;
        cursor[i] = run;
        run += counts[i];
    }
    if (t == 1023) rowptr[N] = wsum[15];
}

// ---------------- K2c: scatter edges into CSR ------------------------------
__global__ void scatter_k(const int* __restrict__ ei, int* __restrict__ cursor,
                          int* __restrict__ ssrc, int E, int N) {
    int i = blockIdx.x * 256 + threadIdx.x;
    int tot = E + N;
    if (i >= tot) return;
    int s, d;
    if (i < E) { s = ei[i]; d = ei[E + i]; }
    else       { s = i - E; d = s; }
    int pos = atomicAdd(&cursor[d], 1);
    ssrc[pos] = s;
}

// ------- K3: fused layer-1 softmax-aggregate + bias + ReLU + layer-2 -------
// one wave per node, single-pass online softmax, 8-edge unroll, fp16 h.
__global__ __launch_bounds__(256) void agg1_k(const __half* __restrict__ hh,
                                              const float* __restrict__ asrc,
                                              const float* __restrict__ adst,
                                              const int* __restrict__ rowptr,
                                              const int* __restrict__ ssrc,
                                              const float* __restrict__ b1,
                                              const float* __restrict__ W2,
                                              const float* __restrict__ as2,
                                              const float* __restrict__ ad2,
                                              float4* __restrict__ tab2, int N) {
    const int lane = threadIdx.x & 63;
    const int n = blockIdx.x * 4 + (threadIdx.x >> 6);
    if (n >= N) return;
    const int hd = lane >> 3;
    const float adn = adst[n * 8 + hd];
    const int beg = rowptr[n], end = rowptr[n + 1];
    const size_t loff = lane * 4;

    float m = -1e30f, ssum = 0.f;
    float4 acc = make_float4(0.f, 0.f, 0.f, 0.f);
    int j = beg;
    for (; j + 7 < end; j += 8) {
        int s[8];
#pragma unroll
        for (int i = 0; i < 8; ++i) s[i] = ssrc[j + i];
        float2 r[8];
        float a[8];
#pragma unroll
        for (int i = 0; i < 8; ++i) {
            r[i] = *(const float2*)(hh + (size_t)s[i] * C1 + loff);
            float av = asrc[s[i] * 8 + hd] + adn;
            a[i] = (av > 0.f) ? av : NEG * av;
        }
        float mn = m;
#pragma unroll
        for (int i = 0; i < 8; ++i) mn = fmaxf(mn, a[i]);
        float c = __expf(m - mn);
        float es = 0.f;
        float4 add = make_float4(0.f, 0.f, 0.f, 0.f);
#pragma unroll
        for (int i = 0; i < 8; ++i) {
            float ev = __expf(a[i] - mn);
            es += ev;
            const __half2* p = (const __half2*)&r[i];
            float2 fa = __half22float2(p[0]);
            float2 fb = __half22float2(p[1]);
            add.x += fa.x * ev;
            add.y += fa.y * ev;
            add.z += fb.x * ev;
            add.w += fb.y * ev;
        }
        ssum = ssum * c + es;
        acc.x = acc.x * c + add.x;
        acc.y = acc.y * c + add.y;
        acc.z = acc.z * c + add.z;
        acc.w = acc.w * c + add.w;
        m = mn;
    }
    for (; j < end; ++j) {
        int s0 = ssrc[j];
        float2 r0 = *(const float2*)(hh + (size_t)s0 * C1 + loff);
        float a0 = asrc[s0 * 8 + hd] + adn;
        a0 = (a0 > 0.f) ? a0 : NEG * a0;
        float mn = fmaxf(m, a0);
        float c = __expf(m - mn);
        float e0 = __expf(a0 - mn);
        const __half2* p0 = (const __half2*)&r0;
        float2 f0a = __half22float2(p0[0]), f0b = __half22float2(p0[1]);
        ssum = ssum * c + e0;
        acc.x = acc.x * c + f0a.x * e0;
        acc.y = acc.y * c + f0a.y * e0;
        acc.z = acc.z * c + f0b.x * e0;
        acc.w = acc.w * c + f0b.y * e0;
        m = mn;
    }

    const float inv = 1.f / ssum;
    float4 bv = *(const float4*)(b1 + lane * 4);
    float o0 = fmaxf(acc.x * inv + bv.x, 0.f);
    float o1 = fmaxf(acc.y * inv + bv.y, 0.f);
    float o2 = fmaxf(acc.z * inv + bv.z, 0.f);
    float o3 = fmaxf(acc.w * inv + bv.w, 0.f);

    float4 w20 = *(const float4*)(W2 + lane * 8);
    float4 w21 = *(const float4*)(W2 + lane * 8 + 4);
    float p0 = o0 * w20.x + o1 * w20.z + o2 * w21.x + o3 * w21.z;
    float p1 = o0 * w20.y + o1 * w20.w + o2 * w21.y + o3 * w21.w;
#pragma unroll
    for (int off = 1; off < 64; off <<= 1) {
        p0 += __shfl_xor(p0, off);
        p1 += __shfl_xor(p1, off);
    }
    if (lane == 0) {
        float a2s = p0 * as2[0] + p1 * as2[1];
        float a2d = p0 * ad2[0] + p1 * ad2[1];
        tab2[n] = make_float4(p0, p1, a2s, a2d);
    }
}

// ---------------- K4: layer-2 aggregation (8 lanes / node) -----------------
__global__ __launch_bounds__(256) void agg2_k(const int* __restrict__ rowptr,
                                              const int* __restrict__ ssrc,
                                              const float4* __restrict__ tab2,
                                              const float* __restrict__ b2,
                                              float* __restrict__ out, int N) {
    const int t = threadIdx.x;
    const int sub = t & 7;
    const int n = blockIdx.x * 32 + (t >> 3);
    if (n >= N) return;
    const float a2d = tab2[n].w;
    const int beg = rowptr[n], end = rowptr[n + 1];
    float m = -1e30f, ssum = 0.f, a0 = 0.f, a1 = 0.f;
    for (int j = beg + sub; j < end; j += 8) {
        float4 tv = tab2[ssrc[j]];
        float a = tv.z + a2d;
        a = (a > 0.f) ? a : NEG * a;
        float mn = fmaxf(m, a);
        float c = __expf(m - mn);
        float ev = __expf(a - mn);
        ssum = ssum * c + ev;
        a0 = a0 * c + tv.x * ev;
        a1 = a1 * c + tv.y * ev;
        m = mn;
    }
#pragma unroll
    for (int off = 1; off < 8; off <<= 1) {
        float mo = __shfl_xor(m, off);
        float so = __shfl_xor(ssum, off);
        float x0 = __shfl_xor(a0, off);
        float x1 = __shfl_xor(a1, off);
        float mn = fmaxf(m, mo);
        float c = __expf(m - mn), co = __expf(mo - mn);
        ssum = ssum * c + so * co;
        a0 = a0 * c + x0 * co;
        a1 = a1 * c + x1 * co;
        m = mn;
    }
    if (sub == 0) {
        float inv = 1.f / ssum;
        out[(size_t)n * 2 + 0] = a0 * inv + b2[0];
        out[(size_t)n * 2 + 1] = a1 * inv + b2[1];
    }
}

extern "C" void kernel_launch(void* const* d_in, const int* in_sizes, int n_in,
                              void* d_out, int out_size, void* d_ws, size_t ws_size,
                              hipStream_t stream) {
    const float* x   = (const float*)d_in[0];
    const int*   ei  = (const int*)d_in[1];
    const float* W1  = (const float*)d_in[2];
    const float* at_s1 = (const float*)d_in[3];
    const float* at_d1 = (const float*)d_in[4];
    const float* b1  = (const float*)d_in[5];
    const float* W2  = (const float*)d_in[6];
    const float* at_s2 = (const float*)d_in[7];
    const float* at_d2 = (const float*)d_in[8];
    const float* b2  = (const float*)d_in[9];
    float* out = (float*)d_out;

    const int N = in_sizes[0] / F_IN;
    const int E = in_sizes[1] / 2;
    const int TOT = E + N;

    char* ws = (char*)d_ws;
    size_t off = 0;
    auto alloc = [&](size_t bytes) -> void* {
        void* p = ws + off;
        off = (off + bytes + 255) & ~(size_t)255;
        return p;
    };
    __half* hh     = (__half*)alloc((size_t)N * C1 * 2);
    float*  asrc   = (float*)alloc((size_t)N * 8 * 4);
    float*  adst   = (float*)alloc((size_t)N * 8 * 4);
    int*    counts = (int*)alloc((size_t)N * 4);
    int*    rowptr = (int*)alloc((size_t)(N + 1) * 4);
    int*    cursor = (int*)alloc((size_t)N * 4);
    int*    ssrc   = (int*)alloc((size_t)TOT * 4);
    float4* tab2   = (float4*)alloc((size_t)N * 16);

    hipMemsetAsync(counts, 0, (size_t)N * 4, stream);

    gemm1_k<<<(N + 63) / 64, 256, 0, stream>>>(x, W1, hh, N);
    attcoef1_k<<<(N + 3) / 4, 256, 0, stream>>>(hh, at_s1, at_d1, asrc, adst, N);
    hist_k<<<(TOT + 255) / 256, 256, 0, stream>>>(ei, counts, E, N);
    scan_k<<<1, 1024, 0, stream>>>(counts, rowptr, cursor, N);
    scatter_k<<<(TOT + 255) / 256, 256, 0, stream>>>(ei, cursor, ssrc, E, N);
    agg1_k<<<(N + 3) / 4, 256, 0, stream>>>(hh, asrc, adst, rowptr, ssrc,
                                            b1, W2, at_s2, at_d2, tab2, N);
    agg2_k<<<(N + 31) / 32, 256, 0, stream>>>(rowptr, ssrc, tab2, b2, out, N);
}

// Round 5
// 234.116 us; speedup vs baseline: 1.9386x; 1.0570x over previous
//
#include <hip/hip_runtime.h>
#include <hip/hip_fp16.h>

#define F_IN 128
#define C1 256
#define NEG 0.2f
#define LOG2E 1.4426950408889634f

typedef _Float16 f16x8 __attribute__((ext_vector_type(8)));
typedef _Float16 f16x4 __attribute__((ext_vector_type(4)));
typedef float f32x4 __attribute__((ext_vector_type(4)));

#define XS_LD 136  // 128 + 8 f16 pad

// ---- K1 fused: [blocks 0..nbg) gemm x@W1 -> h fp16 + att coefs (log2e-scaled)
//      [blocks nbg..) histogram of dst
__global__ __launch_bounds__(256) void gemm_att_hist_k(
        const float* __restrict__ x, const float* __restrict__ W,
        const float* __restrict__ att_s, const float* __restrict__ att_d,
        __half* __restrict__ hh, float* __restrict__ asrc, float* __restrict__ adst,
        const int* __restrict__ ei, int* __restrict__ counts,
        int N, int E, int nbg) {
    if (blockIdx.x >= nbg) {
        // ---------------- histogram part ----------------
        int i = (blockIdx.x - nbg) * 256 + threadIdx.x;
        int tot = E + N;
        if (i < tot) {
            int d = (i < E) ? ei[E + i] : (i - E);
            atomicAdd(&counts[d], 1);
        }
        return;
    }
    // ---------------- GEMM + att part ----------------
    __shared__ _Float16 xs[64 * XS_LD];
    const int t = threadIdx.x;
    const int row0 = blockIdx.x * 64;
    {
        const int r = t >> 2;
        const int c0 = (t & 3) * 32;
        const int gr = row0 + r;
        _Float16* dst = xs + r * XS_LD + c0;
        if (gr < N) {
            const float4* px = (const float4*)(x + (size_t)gr * F_IN + c0);
#pragma unroll
            for (int i = 0; i < 8; ++i) {
                float4 v = px[i];
                f16x4 w;
                w[0] = (_Float16)v.x; w[1] = (_Float16)v.y;
                w[2] = (_Float16)v.z; w[3] = (_Float16)v.w;
                *(f16x4*)(dst + i * 4) = w;
            }
        } else {
            f16x4 z = {0, 0, 0, 0};
#pragma unroll
            for (int i = 0; i < 8; ++i) *(f16x4*)(dst + i * 4) = z;
        }
    }
    __syncthreads();

    const int wid = t >> 6;
    const int lane = t & 63;
    const int l15 = lane & 15;
    const int grp = lane >> 4;
    f32x4 acc[16];
#pragma unroll
    for (int i = 0; i < 16; ++i) acc[i] = (f32x4){0.f, 0.f, 0.f, 0.f};

    const _Float16* arow_p = xs + (wid * 16 + l15) * XS_LD;
#pragma unroll
    for (int ks = 0; ks < 4; ++ks) {
        f16x8 afr = *(const f16x8*)(arow_p + ks * 32 + grp * 8);
        const float* wbase = W + (size_t)(ks * 32 + grp * 8) * C1 + l15;
#pragma unroll
        for (int ct = 0; ct < 16; ++ct) {
            const float* wp = wbase + ct * 16;
            f16x8 bfr;
#pragma unroll
            for (int e = 0; e < 8; ++e)
                bfr[e] = (_Float16)wp[(size_t)e * C1];
            acc[ct] = __builtin_amdgcn_mfma_f32_16x16x32_f16(afr, bfr, acc[ct], 0, 0, 0);
        }
    }
    // store h fp16 ; D: col = ct*16+l15, row = grp*4 + reg
#pragma unroll
    for (int ct = 0; ct < 16; ++ct) {
#pragma unroll
        for (int i = 0; i < 4; ++i) {
            int gr = row0 + wid * 16 + grp * 4 + i;
            if (gr < N) hh[(size_t)gr * C1 + ct * 16 + l15] = __float2half_rn(acc[ct][i]);
        }
    }
    // attention coefficients from f32 accumulators.
    // thread holds cols ct*16+l15; head(col) = ct>>1; in-head idx = (ct&1)*16+l15.
    float as_v[16], ad_v[16];
#pragma unroll
    for (int ct = 0; ct < 16; ++ct) {
        as_v[ct] = att_s[ct * 16 + l15];
        ad_v[ct] = att_d[ct * 16 + l15];
    }
#pragma unroll
    for (int i = 0; i < 4; ++i) {
        float my_s = 0.f, my_d = 0.f;
#pragma unroll
        for (int hd = 0; hd < 8; ++hd) {
            float p = acc[2 * hd][i] * as_v[2 * hd] + acc[2 * hd + 1][i] * as_v[2 * hd + 1];
            float q = acc[2 * hd][i] * ad_v[2 * hd] + acc[2 * hd + 1][i] * ad_v[2 * hd + 1];
#pragma unroll
            for (int off = 1; off < 16; off <<= 1) {
                p += __shfl_xor(p, off);
                q += __shfl_xor(q, off);
            }
            if (l15 == hd) { my_s = p; my_d = q; }
        }
        int gr = row0 + wid * 16 + grp * 4 + i;
        if (gr < N && l15 < 8) {
            asrc[gr * 8 + l15] = my_s * LOG2E;
            adst[gr * 8 + l15] = my_d * LOG2E;
        }
    }
}

// ---------------- K2b: single-block scan -> rowptr, cursor -----------------
__global__ __launch_bounds__(1024) void scan_k(const int* __restrict__ counts,
                                               int* __restrict__ rowptr,
                                               int* __restrict__ cursor, int N) {
    __shared__ int wsum[16];
    const int t = threadIdx.x;
    const int lane = t & 63;
    const int wid = t >> 6;
    const int CH = ((N + 1023) / 1024 + 3) & ~3;
    const int b = t * CH;
    const int e = min(b + CH, N);
    int s = 0;
    int i = b;
    for (; i + 4 <= e; i += 4) {
        int4 v = *(const int4*)(counts + i);
        s += v.x + v.y + v.z + v.w;
    }
    for (; i < e; ++i) s += counts[i];

    int v = s;
#pragma unroll
    for (int off = 1; off < 64; off <<= 1) {
        int u = __shfl_up(v, off);
        if (lane >= off) v += u;
    }
    if (lane == 63) wsum[wid] = v;
    __syncthreads();
    if (t < 16) {
        int w = wsum[t];
#pragma unroll
        for (int off = 1; off < 16; off <<= 1) {
            int u = __shfl_up(w, off);
            if (t >= off) w += u;
        }
        wsum[t] = w;
    }
    __syncthreads();
    int run = v - s + ((wid > 0) ? wsum[wid - 1] : 0);
    i = b;
    for (; i + 4 <= e; i += 4) {
        int4 c = *(const int4*)(counts + i);
        int4 w;
        w.x = run;
        w.y = w.x + c.x;
        w.z = w.y + c.y;
        w.w = w.z + c.z;
        run = w.w + c.w;
        *(int4*)(rowptr + i) = w;
        *(int4*)(cursor + i) = w;
    }
    for (; i < e; ++i) {
        rowptr[i] = run;
        cursor[i] = run;
        run += counts[i];
    }
    if (t == 1023) rowptr[N] = wsum[15];
}

// ---------------- K2c: scatter edges into CSR ------------------------------
__global__ void scatter_k(const int* __restrict__ ei, int* __restrict__ cursor,
                          int* __restrict__ ssrc, int E, int N) {
    int i = blockIdx.x * 256 + threadIdx.x;
    int tot = E + N;
    if (i >= tot) return;
    int s, d;
    if (i < E) { s = ei[i]; d = ei[E + i]; }
    else       { s = i - E; d = s; }
    int pos = atomicAdd(&cursor[d], 1);
    ssrc[pos] = s;
}

// ------- K3: fused layer-1 softmax-aggregate + bias + ReLU + layer-2 -------
// one wave per node; online softmax in exp2 domain; defer-max; fma_mix accums.
__global__ __launch_bounds__(256) void agg1_k(const __half* __restrict__ hh,
                                              const float* __restrict__ asrc,
                                              const float* __restrict__ adst,
                                              const int* __restrict__ rowptr,
                                              const int* __restrict__ ssrc,
                                              const float* __restrict__ b1,
                                              const float* __restrict__ W2,
                                              const float* __restrict__ as2,
                                              const float* __restrict__ ad2,
                                              float4* __restrict__ tab2, int N) {
    const int lane = threadIdx.x & 63;
    const int n = blockIdx.x * 4 + (threadIdx.x >> 6);
    if (n >= N) return;
    const int hd = lane >> 3;
    const float adn = adst[n * 8 + hd];          // log2e-scaled
    const int beg = rowptr[n], end = rowptr[n + 1];
    const char* hb = (const char*)hh;
    const char* ab = (const char*)asrc;
    const int lboff = lane * 8;
    const int hoff = hd * 4;

    float m = -1e30f, ssum = 0.f;
    float4 acc = make_float4(0.f, 0.f, 0.f, 0.f);
    int j = beg;
    for (; j + 3 < end; j += 4) {
        int s0 = ssrc[j], s1 = ssrc[j + 1], s2 = ssrc[j + 2], s3 = ssrc[j + 3];
        f16x4 h0 = *(const f16x4*)(hb + (s0 << 9) + lboff);
        f16x4 h1 = *(const f16x4*)(hb + (s1 << 9) + lboff);
        f16x4 h2 = *(const f16x4*)(hb + (s2 << 9) + lboff);
        f16x4 h3 = *(const f16x4*)(hb + (s3 << 9) + lboff);
        float a0 = *(const float*)(ab + (s0 << 5) + hoff) + adn; a0 = (a0 > 0.f) ? a0 : NEG * a0;
        float a1 = *(const float*)(ab + (s1 << 5) + hoff) + adn; a1 = (a1 > 0.f) ? a1 : NEG * a1;
        float a2 = *(const float*)(ab + (s2 << 5) + hoff) + adn; a2 = (a2 > 0.f) ? a2 : NEG * a2;
        float a3 = *(const float*)(ab + (s3 << 5) + hoff) + adn; a3 = (a3 > 0.f) ? a3 : NEG * a3;
        float mn = fmaxf(fmaxf(fmaxf(a0, a1), fmaxf(a2, a3)), m);
        if (__any(mn > m)) {
            float c = exp2f(m - mn);
            ssum *= c; acc.x *= c; acc.y *= c; acc.z *= c; acc.w *= c;
            m = mn;
        }
        float e0 = exp2f(a0 - m), e1 = exp2f(a1 - m);
        float e2 = exp2f(a2 - m), e3 = exp2f(a3 - m);
        ssum += e0 + e1 + e2 + e3;
        acc.x += (float)h0[0] * e0 + (float)h1[0] * e1 + (float)h2[0] * e2 + (float)h3[0] * e3;
        acc.y += (float)h0[1] * e0 + (float)h1[1] * e1 + (float)h2[1] * e2 + (float)h3[1] * e3;
        acc.z += (float)h0[2] * e0 + (float)h1[2] * e1 + (float)h2[2] * e2 + (float)h3[2] * e3;
        acc.w += (float)h0[3] * e0 + (float)h1[3] * e1 + (float)h2[3] * e2 + (float)h3[3] * e3;
    }
    for (; j < end; ++j) {
        int s0 = ssrc[j];
        f16x4 h0 = *(const f16x4*)(hb + (s0 << 9) + lboff);
        float a0 = *(const float*)(ab + (s0 << 5) + hoff) + adn; a0 = (a0 > 0.f) ? a0 : NEG * a0;
        float mn = fmaxf(m, a0);
        if (__any(mn > m)) {
            float c = exp2f(m - mn);
            ssum *= c; acc.x *= c; acc.y *= c; acc.z *= c; acc.w *= c;
            m = mn;
        }
        float e0 = exp2f(a0 - m);
        ssum += e0;
        acc.x += (float)h0[0] * e0;
        acc.y += (float)h0[1] * e0;
        acc.z += (float)h0[2] * e0;
        acc.w += (float)h0[3] * e0;
    }

    const float inv = 1.f / ssum;
    float4 bv = *(const float4*)(b1 + lane * 4);
    float o0 = fmaxf(acc.x * inv + bv.x, 0.f);
    float o1 = fmaxf(acc.y * inv + bv.y, 0.f);
    float o2 = fmaxf(acc.z * inv + bv.z, 0.f);
    float o3 = fmaxf(acc.w * inv + bv.w, 0.f);

    float4 w20 = *(const float4*)(W2 + lane * 8);
    float4 w21 = *(const float4*)(W2 + lane * 8 + 4);
    float p0 = o0 * w20.x + o1 * w20.z + o2 * w21.x + o3 * w21.z;
    float p1 = o0 * w20.y + o1 * w20.w + o2 * w21.y + o3 * w21.w;
#pragma unroll
    for (int off = 1; off < 64; off <<= 1) {
        p0 += __shfl_xor(p0, off);
        p1 += __shfl_xor(p1, off);
    }
    if (lane == 0) {
        float a2s = (p0 * as2[0] + p1 * as2[1]) * LOG2E;
        float a2d = (p0 * ad2[0] + p1 * ad2[1]) * LOG2E;
        tab2[n] = make_float4(p0, p1, a2s, a2d);
    }
}

// ---------------- K4: layer-2 aggregation (8 lanes / node) -----------------
__global__ __launch_bounds__(256) void agg2_k(const int* __restrict__ rowptr,
                                              const int* __restrict__ ssrc,
                                              const float4* __restrict__ tab2,
                                              const float* __restrict__ b2,
                                              float* __restrict__ out, int N) {
    const int t = threadIdx.x;
    const int sub = t & 7;
    const int n = blockIdx.x * 32 + (t >> 3);
    if (n >= N) return;
    const float a2d = tab2[n].w;
    const int beg = rowptr[n], end = rowptr[n + 1];
    float m = -1e30f, ssum = 0.f, a0 = 0.f, a1 = 0.f;
    for (int j = beg + sub; j < end; j += 8) {
        float4 tv = tab2[ssrc[j]];
        float a = tv.z + a2d;
        a = (a > 0.f) ? a : NEG * a;
        float mn = fmaxf(m, a);
        float c = exp2f(m - mn);
        float ev = exp2f(a - mn);
        ssum = ssum * c + ev;
        a0 = a0 * c + tv.x * ev;
        a1 = a1 * c + tv.y * ev;
        m = mn;
    }
#pragma unroll
    for (int off = 1; off < 8; off <<= 1) {
        float mo = __shfl_xor(m, off);
        float so = __shfl_xor(ssum, off);
        float x0 = __shfl_xor(a0, off);
        float x1 = __shfl_xor(a1, off);
        float mn = fmaxf(m, mo);
        float c = exp2f(m - mn), co = exp2f(mo - mn);
        ssum = ssum * c + so * co;
        a0 = a0 * c + x0 * co;
        a1 = a1 * c + x1 * co;
        m = mn;
    }
    if (sub == 0) {
        float inv = 1.f / ssum;
        out[(size_t)n * 2 + 0] = a0 * inv + b2[0];
        out[(size_t)n * 2 + 1] = a1 * inv + b2[1];
    }
}

extern "C" void kernel_launch(void* const* d_in, const int* in_sizes, int n_in,
                              void* d_out, int out_size, void* d_ws, size_t ws_size,
                              hipStream_t stream) {
    const float* x   = (const float*)d_in[0];
    const int*   ei  = (const int*)d_in[1];
    const float* W1  = (const float*)d_in[2];
    const float* at_s1 = (const float*)d_in[3];
    const float* at_d1 = (const float*)d_in[4];
    const float* b1  = (const float*)d_in[5];
    const float* W2  = (const float*)d_in[6];
    const float* at_s2 = (const float*)d_in[7];
    const float* at_d2 = (const float*)d_in[8];
    const float* b2  = (const float*)d_in[9];
    float* out = (float*)d_out;

    const int N = in_sizes[0] / F_IN;
    const int E = in_sizes[1] / 2;
    const int TOT = E + N;

    char* ws = (char*)d_ws;
    size_t off = 0;
    auto alloc = [&](size_t bytes) -> void* {
        void* p = ws + off;
        off = (off + bytes + 255) & ~(size_t)255;
        return p;
    };
    __half* hh     = (__half*)alloc((size_t)N * C1 * 2);
    float*  asrc   = (float*)alloc((size_t)N * 8 * 4);
    float*  adst   = (float*)alloc((size_t)N * 8 * 4);
    int*    counts = (int*)alloc((size_t)N * 4);
    int*    rowptr = (int*)alloc((size_t)(N + 1) * 4);
    int*    cursor = (int*)alloc((size_t)N * 4);
    int*    ssrc   = (int*)alloc((size_t)TOT * 4);
    float4* tab2   = (float4*)alloc((size_t)N * 16);

    hipMemsetAsync(counts, 0, (size_t)N * 4, stream);

    const int nbg = (N + 63) / 64;
    const int nbh = (TOT + 255) / 256;
    gemm_att_hist_k<<<nbg + nbh, 256, 0, stream>>>(x, W1, at_s1, at_d1, hh,
                                                   asrc, adst, ei, counts, N, E, nbg);
    scan_k<<<1, 1024, 0, stream>>>(counts, rowptr, cursor, N);
    scatter_k<<<(TOT + 255) / 256, 256, 0, stream>>>(ei, cursor, ssrc, E, N);
    agg1_k<<<(N + 3) / 4, 256, 0, stream>>>(hh, asrc, adst, rowptr, ssrc,
                                            b1, W2, at_s2, at_d2, tab2, N);
    agg2_k<<<(N + 31) / 32, 256, 0, stream>>>(rowptr, ssrc, tab2, b2, out, N);
}